// Round 7
// baseline (87.466 us; speedup 1.0000x reference)
//
#include <hip/hip_runtime.h>
#include <hip/hip_bf16.h>

// x [16,64,256,256] f32, haar [256,256] f32 -> out [16,64,128,128] f32.
// out[b,c2,i2,j2] = res[b, i2&63, 4*c2+(i2>>6), j2], res = X @ (haar@haar).
// Only x-rows i%4 in {0,1} and cols j<128 of res are needed.
// m = selected-row index (0..127): i = ((m>>1)<<2)|(m&1);
// store: out[((b*64+(m>>1))*128 + (m&1)*64 + c)*128 + j].

typedef __attribute__((ext_vector_type(8))) short bf16x8;
typedef __attribute__((ext_vector_type(4))) float f32x4;

#define H2_MAGIC 0x5EED0001u

static __device__ inline unsigned short bf16bits(float f) {
    __hip_bfloat16 h = __float2bfloat16(f);
    return *reinterpret_cast<unsigned short*>(&h);
}

// ------------------------------------------------------------------ kernel 1
// B_swz: H2[k][n] = sum_t haar[k][t]*haar[t][n], n in [0,128), bf16, stored in
// MFMA-fragment order with COLUMN-PERMUTED fragment slots:
//   frag fb, lane-col lr covers output column n = (fb>>2)*64 + lr*4 + (fb&3).
// idx = (((fb*8+s)*64 + lg*16 + lr)<<3) + e, where k = s*32 + lg*8 + e.
// After its 128 stores, each block release-publishes flags[k] = H2_MAGIC.
__global__ void h2swz_kernel(const float* __restrict__ haar,
                             unsigned short* __restrict__ bswz,
                             unsigned int* __restrict__ flags) {
    __shared__ float rowk[256];
    __shared__ float part[128];
    const int k   = blockIdx.x;     // 0..255
    const int tid = threadIdx.x;    // 0..255
    const int n   = tid & 127;
    const int h   = tid >> 7;       // t-half
    rowk[tid] = haar[k * 256 + tid];
    __syncthreads();
    float a0 = 0.f, a1 = 0.f, a2 = 0.f, a3 = 0.f;
    const int t0 = h * 128;
#pragma unroll 8
    for (int t = 0; t < 128; t += 4) {
        a0 = fmaf(rowk[t0 + t + 0], haar[(t0 + t + 0) * 256 + n], a0);
        a1 = fmaf(rowk[t0 + t + 1], haar[(t0 + t + 1) * 256 + n], a1);
        a2 = fmaf(rowk[t0 + t + 2], haar[(t0 + t + 2) * 256 + n], a2);
        a3 = fmaf(rowk[t0 + t + 3], haar[(t0 + t + 3) * 256 + n], a3);
    }
    const float acc = (a0 + a1) + (a2 + a3);
    if (h) part[n] = acc;
    __syncthreads();
    if (!h) {
        const int hi = n >> 6, lr = (n & 63) >> 2, q = n & 3;
        const int fb = hi * 4 + q;
        const int s = k >> 5, lg = (k >> 3) & 3, e = k & 7;
        const size_t idx = ((((size_t)(fb * 8 + s)) * 64 + lg * 16 + lr) << 3) + e;
        bswz[idx] = bf16bits(acc + part[n]);
    }
    __threadfence();    // each thread's stores visible at device scope
    __syncthreads();    // whole block's stores done
    if (tid == 0)
        __hip_atomic_store(&flags[k], H2_MAGIC, __ATOMIC_RELEASE,
                           __HIP_MEMORY_SCOPE_AGENT);
}

// ------------------------------------------------------------------ kernel 2
// Persistent: grid 256 (1 block/CU, 128 KB LDS), 512 threads = 8 waves.
// Spin-waits on kernel 1's flags (k1 co-resident: it needs only 1.5 KB LDS /
// 4 waves; k2 leaves 32 KB + 24 wave slots free per CU).  Replays may find
// flags already set; k1 rewrites identical bytes, so that is benign.
// Then: each block processes 4 matrices (blk = bid*4+it), depth-2 register
// pipeline; compute phase consumes LDS only (vmcnt belongs to staging alone).
// Wave w owns sel-rows [w*16,+16) x all 128 cols; reads only LDS rows it
// wrote itself -> no per-item barrier.
__global__ __launch_bounds__(512, 2)
void wavelet_gemm_kernel(const float* __restrict__ x,
                         const uint4* __restrict__ bswz16,
                         const unsigned int* __restrict__ flags,
                         float* __restrict__ out) {
    __shared__ __align__(16) char lds[131072];   // A swz rows [0,64K); B [64K,128K)
    const int tid  = threadIdx.x;
    const int lane = tid & 63;
    const int w    = tid >> 6;        // 0..7
    const int lr   = lane & 15;
    const int lg   = lane >> 4;

    // ---- wait for the H2 table (no vmem issued before this point) ----
    {
        const unsigned int* f = flags + (tid >> 1);   // 2 threads per flag
        while (__hip_atomic_load(f, __ATOMIC_RELAXED,
                                 __HIP_MEMORY_SCOPE_AGENT) != H2_MAGIC) {}
        __syncthreads();
        __builtin_amdgcn_fence(__ATOMIC_ACQUIRE, "agent");  // invalidate stale L1
    }

    const int mat0 = blockIdx.x * 4;

    // ---- prologue: issue item-0/1 A row loads (dense 1KB, nontemporal) ----
    f32x4 rvA[16], rvB[16];
#pragma unroll
    for (int q = 0; q < 16; ++q) {
        const int m = w * 16 + q;
        const int i = ((m >> 1) << 2) | (m & 1);
        rvA[q] = __builtin_nontemporal_load(
            reinterpret_cast<const f32x4*>(x + (size_t)mat0 * 65536 + i * 256) + lane);
    }
#pragma unroll
    for (int q = 0; q < 16; ++q) {
        const int m = w * 16 + q;
        const int i = ((m >> 1) << 2) | (m & 1);
        rvB[q] = __builtin_nontemporal_load(
            reinterpret_cast<const f32x4*>(x + (size_t)(mat0 + 1) * 65536 + i * 256) + lane);
    }

    // ---- stage B table into LDS (64 KB, frag-order preserved) ----
    {
        uint4* bdst = reinterpret_cast<uint4*>(lds + 65536);
#pragma unroll
        for (int r = 0; r < 8; ++r)
            bdst[r * 512 + tid] = bswz16[r * 512 + tid];
    }

    __syncthreads();   // B table ready

#pragma unroll
    for (int it = 0; it < 4; ++it) {
        const int blk = mat0 + it;            // b*64 + c
        const int c = blk & 63, b = blk >> 6;
        f32x4* cur = (it & 1) ? rvB : rvA;    // statically resolved (unrolled)

        // ---- cvt + write A rows to swizzled LDS (drains this item's loads) ----
#pragma unroll
        for (int q = 0; q < 16; ++q) {
            const int lm = w * 16 + q;
            union { unsigned short u[4]; unsigned long long d; } p;
            p.u[0] = bf16bits(cur[q].x);
            p.u[1] = bf16bits(cur[q].y);
            p.u[2] = bf16bits(cur[q].z);
            p.u[3] = bf16bits(cur[q].w);      // lane covers k = 4*lane..4*lane+3
            const int byte = (lm * 512 + lane * 8) ^ ((lm & 7) << 4);
            *reinterpret_cast<unsigned long long*>(lds + byte) = p.d;
        }

        // ---- refill the just-consumed buffer with item it+2 ----
        if (it < 2) {
            const float* xb = x + (size_t)(blk + 2) * 65536;
#pragma unroll
            for (int q = 0; q < 16; ++q) {
                const int m = w * 16 + q;
                const int i = ((m >> 1) << 2) | (m & 1);
                cur[q] = __builtin_nontemporal_load(
                    reinterpret_cast<const f32x4*>(xb + i * 256) + lane);
            }
        }

        // ---- compute: 8 k-steps, all-LDS operands, 8 MFMA each ----
        f32x4 acc[8] = {};
#pragma unroll
        for (int s = 0; s < 8; ++s) {
            const int lm = w * 16 + lr;
            const int abyte = (lm * 512 + s * 64 + lg * 16) ^ ((lm & 7) << 4);
            const bf16x8 aF = *reinterpret_cast<const bf16x8*>(lds + abyte);
#pragma unroll
            for (int fb = 0; fb < 8; ++fb) {
                const bf16x8 bF = *reinterpret_cast<const bf16x8*>(
                    lds + 65536 + (((fb * 8 + s) * 64 + lane) << 4));
                acc[fb] = __builtin_amdgcn_mfma_f32_16x16x32_bf16(aF, bF, acc[fb], 0, 0, 0);
            }
        }

        // ---- epilogue: C/D row=(lane>>4)*4+r; lane lr holds j = hi*64+lr*4+q
        // in acc[hi*4+q][r] -> two dense f32x4 stores per r.
#pragma unroll
        for (int r = 0; r < 4; ++r) {
            const int m = w * 16 + lg * 4 + r;
            float* rowp = out + (((size_t)b * 64 + (m >> 1)) * 128 + (m & 1) * 64 + c) * 128;
            f32x4 v0 = {acc[0][r], acc[1][r], acc[2][r], acc[3][r]};
            f32x4 v1 = {acc[4][r], acc[5][r], acc[6][r], acc[7][r]};
            *reinterpret_cast<f32x4*>(rowp + lr * 4)      = v0;
            *reinterpret_cast<f32x4*>(rowp + 64 + lr * 4) = v1;
        }
    }
}

extern "C" void kernel_launch(void* const* d_in, const int* in_sizes, int n_in,
                              void* d_out, int out_size, void* d_ws, size_t ws_size,
                              hipStream_t stream) {
    const float* x    = (const float*)d_in[0];
    const float* haar = (const float*)d_in[1];
    float* out = (float*)d_out;
    unsigned short* bswz = (unsigned short*)d_ws;               // [0, 64 KB)
    unsigned int* flags  = (unsigned int*)((char*)d_ws + 65536); // 256 x u32

    h2swz_kernel<<<dim3(256), dim3(256), 0, stream>>>(haar, bswz, flags);
    wavelet_gemm_kernel<<<dim3(256), dim3(512), 0, stream>>>(
        x, reinterpret_cast<const uint4*>(bswz), flags, out);
}

// Round 8
// 40.213 us; speedup vs baseline: 2.1751x; 2.1751x over previous
//
#include <hip/hip_runtime.h>
#include <hip/hip_bf16.h>

// x [16,64,256,256] f32, haar [256,256] f32 -> out [16,64,128,128] f32.
// out[b,c2,i2,j2] = res[b, i2&63, 4*c2+(i2>>6), j2], res = X @ (haar@haar).
// Only x-rows i%4 in {0,1} and cols j<128 of res are needed.
// m = selected-row index (0..127): i = ((m>>1)<<2)|(m&1);
// store: out[((b*64+(m>>1))*128 + (m&1)*64 + c)*128 + j].
// NOTE (session lesson): __builtin_nontemporal_load on the x stream regressed
// ~40 us twice (rounds 2 & 7) -> plain loads only.

typedef __attribute__((ext_vector_type(8))) short bf16x8;
typedef __attribute__((ext_vector_type(4))) float f32x4;

static __device__ inline unsigned short bf16bits(float f) {
    __hip_bfloat16 h = __float2bfloat16(f);
    return *reinterpret_cast<unsigned short*>(&h);
}

// ------------------------------------------------------------------ kernel 1
// B_swz: H2[k][n] = sum_t haar[k][t]*haar[t][n], n in [0,128), bf16, stored in
// MFMA-fragment order with COLUMN-PERMUTED fragment slots:
//   frag fb, lane-col lr covers output column n = (fb>>2)*64 + lr*4 + (fb&3)
//   (so each lane holds 4 consecutive j -> dwordx4 stores in kernel 2).
// idx = (((fb*8+s)*64 + lg*16 + lr)<<3) + e, where k = s*32 + lg*8 + e.
// 512 threads: 4-way t-split (chain depth 16x4) + LDS reduce.
__global__ void h2swz_kernel(const float* __restrict__ haar,
                             unsigned short* __restrict__ bswz) {
    __shared__ float rowk[256];
    __shared__ float part[3][128];
    const int k   = blockIdx.x;     // 0..255
    const int tid = threadIdx.x;    // 0..511
    const int n   = tid & 127;
    const int g   = tid >> 7;       // t-quarter 0..3
    if (tid < 256) rowk[tid] = haar[k * 256 + tid];
    __syncthreads();
    float a0 = 0.f, a1 = 0.f, a2 = 0.f, a3 = 0.f;
    const int t0 = g * 64;
#pragma unroll
    for (int t = 0; t < 64; t += 4) {
        a0 = fmaf(rowk[t0 + t + 0], haar[(t0 + t + 0) * 256 + n], a0);
        a1 = fmaf(rowk[t0 + t + 1], haar[(t0 + t + 1) * 256 + n], a1);
        a2 = fmaf(rowk[t0 + t + 2], haar[(t0 + t + 2) * 256 + n], a2);
        a3 = fmaf(rowk[t0 + t + 3], haar[(t0 + t + 3) * 256 + n], a3);
    }
    const float acc = (a0 + a1) + (a2 + a3);
    if (g) part[g - 1][n] = acc;
    __syncthreads();
    if (!g) {
        const float v = acc + part[0][n] + part[1][n] + part[2][n];
        const int hi = n >> 6, lr = (n & 63) >> 2, q = n & 3;
        const int fb = hi * 4 + q;
        const int s = k >> 5, lg = (k >> 3) & 3, e = k & 7;
        const size_t idx = ((((size_t)(fb * 8 + s)) * 64 + lg * 16 + lr) << 3) + e;
        bswz[idx] = bf16bits(v);
    }
}

// ------------------------------------------------------------------ kernel 2
// Persistent: grid 256 (1 block/CU, 128 KB LDS), 512 threads = 8 waves.
// Each block processes 4 matrices (blk = bid*4+it), depth-2 register pipeline:
// loads for items it+1 and it+2 stay in flight while item it computes from
// LDS only (compute phase has zero vmcnt dependence).
// Wave w owns sel-rows [w*16, w*16+16) x all 128 cols; reads only LDS rows it
// wrote itself -> no per-item barrier.
__global__ __launch_bounds__(512, 2)
void wavelet_gemm_kernel(const float* __restrict__ x,
                         const uint4* __restrict__ bswz16,
                         float* __restrict__ out) {
    __shared__ __align__(16) char lds[131072];   // A swz rows [0,64K); B [64K,128K)
    const int tid  = threadIdx.x;
    const int lane = tid & 63;
    const int w    = tid >> 6;        // 0..7
    const int lr   = lane & 15;
    const int lg   = lane >> 4;

    // ---- stage B table into LDS (64 KB, frag-order preserved) ----
    {
        uint4* bdst = reinterpret_cast<uint4*>(lds + 65536);
#pragma unroll
        for (int r = 0; r < 8; ++r)
            bdst[r * 512 + tid] = bswz16[r * 512 + tid];
    }

    const int mat0 = blockIdx.x * 4;

    // ---- prologue: issue item-0 and item-1 A row loads (dense 1KB each) ----
    f32x4 rvA[16], rvB[16];
#pragma unroll
    for (int q = 0; q < 16; ++q) {
        const int m = w * 16 + q;
        const int i = ((m >> 1) << 2) | (m & 1);
        rvA[q] = reinterpret_cast<const f32x4*>(x + (size_t)mat0 * 65536 + i * 256)[lane];
    }
#pragma unroll
    for (int q = 0; q < 16; ++q) {
        const int m = w * 16 + q;
        const int i = ((m >> 1) << 2) | (m & 1);
        rvB[q] = reinterpret_cast<const f32x4*>(x + (size_t)(mat0 + 1) * 65536 + i * 256)[lane];
    }

    __syncthreads();   // B table ready

#pragma unroll
    for (int it = 0; it < 4; ++it) {
        const int blk = mat0 + it;            // b*64 + c
        const int c = blk & 63, b = blk >> 6;
        f32x4* cur = (it & 1) ? rvB : rvA;    // statically resolved (unrolled)

        // ---- cvt + write A rows to swizzled LDS (drains this item's loads) ----
#pragma unroll
        for (int q = 0; q < 16; ++q) {
            const int lm = w * 16 + q;
            union { unsigned short u[4]; unsigned long long d; } p;
            p.u[0] = bf16bits(cur[q].x);
            p.u[1] = bf16bits(cur[q].y);
            p.u[2] = bf16bits(cur[q].z);
            p.u[3] = bf16bits(cur[q].w);      // lane covers k = 4*lane..4*lane+3
            const int byte = (lm * 512 + lane * 8) ^ ((lm & 7) << 4);
            *reinterpret_cast<unsigned long long*>(lds + byte) = p.d;
        }

        // ---- refill the just-consumed buffer with item it+2 ----
        if (it < 2) {
            const float* xb = x + (size_t)(blk + 2) * 65536;
#pragma unroll
            for (int q = 0; q < 16; ++q) {
                const int m = w * 16 + q;
                const int i = ((m >> 1) << 2) | (m & 1);
                cur[q] = reinterpret_cast<const f32x4*>(xb + i * 256)[lane];
            }
        }

        // ---- compute: 8 k-steps, all-LDS operands, 8 MFMA each ----
        f32x4 acc[8] = {};
#pragma unroll
        for (int s = 0; s < 8; ++s) {
            const int lm = w * 16 + lr;
            const int abyte = (lm * 512 + s * 64 + lg * 16) ^ ((lm & 7) << 4);
            const bf16x8 aF = *reinterpret_cast<const bf16x8*>(lds + abyte);
#pragma unroll
            for (int fb = 0; fb < 8; ++fb) {
                const bf16x8 bF = *reinterpret_cast<const bf16x8*>(
                    lds + 65536 + (((fb * 8 + s) * 64 + lane) << 4));
                acc[fb] = __builtin_amdgcn_mfma_f32_16x16x32_bf16(aF, bF, acc[fb], 0, 0, 0);
            }
        }

        // ---- epilogue: C/D row=(lane>>4)*4+r; lane lr holds j = hi*64+lr*4+q
        // in acc[hi*4+q][r] -> two dense f32x4 stores per r.
#pragma unroll
        for (int r = 0; r < 4; ++r) {
            const int m = w * 16 + lg * 4 + r;
            float* rowp = out + (((size_t)b * 64 + (m >> 1)) * 128 + (m & 1) * 64 + c) * 128;
            f32x4 v0 = {acc[0][r], acc[1][r], acc[2][r], acc[3][r]};
            f32x4 v1 = {acc[4][r], acc[5][r], acc[6][r], acc[7][r]};
            *reinterpret_cast<f32x4*>(rowp + lr * 4)      = v0;
            *reinterpret_cast<f32x4*>(rowp + 64 + lr * 4) = v1;
        }
    }
}

extern "C" void kernel_launch(void* const* d_in, const int* in_sizes, int n_in,
                              void* d_out, int out_size, void* d_ws, size_t ws_size,
                              hipStream_t stream) {
    const float* x    = (const float*)d_in[0];
    const float* haar = (const float*)d_in[1];
    float* out = (float*)d_out;
    unsigned short* bswz = (unsigned short*)d_ws;   // 64 KB

    h2swz_kernel<<<dim3(256), dim3(512), 0, stream>>>(haar, bswz);
    wavelet_gemm_kernel<<<dim3(256), dim3(512), 0, stream>>>(
        x, reinterpret_cast<const uint4*>(bswz), out);
}